// Round 18
// baseline (339.898 us; speedup 1.0000x reference)
//
#include <hip/hip_runtime.h>

#define NNODES 21844
#define ENC 256
#define HID 1024
#define ROWS 4096   // B*S = 128*32
#define NTIMES 48

typedef __attribute__((ext_vector_type(8))) short bf16x8;
typedef __attribute__((ext_vector_type(8))) unsigned short u16x8;
typedef __attribute__((ext_vector_type(4))) unsigned short u16x4;
typedef __attribute__((ext_vector_type(4))) float f32x4;

__device__ const int g_off[8] = {0, 4, 20, 84, 340, 1364, 5460, 21844};

__device__ inline unsigned short f2bf(float f) {
  unsigned int u = __float_as_uint(f);
  u += 0x7FFF + ((u >> 16) & 1);   // round-to-nearest-even
  return (unsigned short)(u >> 16);
}

__device__ inline int depth_of(int c) {
  return (c >= 4) + (c >= 20) + (c >= 84) + (c >= 340) + (c >= 1364) + (c >= 5460);
}

// ---------------- fused preprocessing: conversions + transposes + S zeroing ----------------
__global__ __launch_bounds__(256) void prep(const float* __restrict__ prefix,
                                            const float* __restrict__ emb,
                                            const float* __restrict__ Wk,
                                            const float* __restrict__ Wt,
                                            unsigned short* __restrict__ Pb16,
                                            unsigned short* __restrict__ Eb,
                                            unsigned short* __restrict__ WkT,
                                            float* __restrict__ WtT,
                                            float* __restrict__ S) {
  int bid = blockIdx.x, tid = threadIdx.x;
  if (bid < 4096) {                          // prefix fp32 -> bf16
    int i = bid * 256 + tid;
    float4 v = reinterpret_cast<const float4*>(prefix)[i];
    ushort4 o; o.x = f2bf(v.x); o.y = f2bf(v.y); o.z = f2bf(v.z); o.w = f2bf(v.w);
    reinterpret_cast<ushort4*>(Pb16)[i] = o;
  } else if (bid < 9557) {                   // emb fp32 -> bf16
    int i = (bid - 4096) * 256 + tid;
    float4 v = reinterpret_cast<const float4*>(emb)[i];
    ushort4 o; o.x = f2bf(v.x); o.y = f2bf(v.y); o.z = f2bf(v.z); o.w = f2bf(v.w);
    reinterpret_cast<ushort4*>(Eb)[i] = o;
  } else if (bid < 10581) {                  // W_key [1024,256] -> bf16 T [256,1024]
    int i = (bid - 9557) * 256 + tid;
    int e = i >> 10, h = i & 1023;
    WkT[i] = f2bf(Wk[h * ENC + e]);
  } else if (bid < 10773) {                  // W_time [48,1024] -> f32 T [1024,48]
    int i = (bid - 10581) * 256 + tid;
    int k = i / NTIMES, c = i % NTIMES;
    WtT[i] = Wt[c * HID + k];
  } else {                                   // zero S (7*4096 floats = 7168 float4)
    int i = (bid - 10773) * 256 + tid;
    reinterpret_cast<float4*>(S)[i] = float4{0.f, 0.f, 0.f, 0.f};
  }
}

// ---------------- P2 = prefix @ W_key  (bf16 MFMA, K=1024) -> bf16 [4096,256] ----------------
__global__ __launch_bounds__(256) void p2_mfma(const unsigned short* __restrict__ Ab,
                                               const unsigned short* __restrict__ Bb,
                                               unsigned short* __restrict__ P2) {
  int lane = threadIdx.x & 63, w = threadIdx.x >> 6;
  int lr = lane & 15, lg = lane >> 4;
  int m0 = blockIdx.y * 64 + w * 16;
  int nb = blockIdx.x * 64;
  f32x4 acc[4];
#pragma unroll
  for (int n = 0; n < 4; ++n) acc[n] = f32x4{0.f, 0.f, 0.f, 0.f};
  const unsigned short* Ap = Ab + (long)(m0 + lr) * HID + lg * 8;
  for (int kk = 0; kk < 32; ++kk) {
    bf16x8 a = *reinterpret_cast<const bf16x8*>(Ap + kk * 32);
#pragma unroll
    for (int n = 0; n < 4; ++n) {
      bf16x8 b = *reinterpret_cast<const bf16x8*>(Bb + (long)(nb + n * 16 + lr) * HID + kk * 32 + lg * 8);
      acc[n] = __builtin_amdgcn_mfma_f32_16x16x32_bf16(a, b, acc[n], 0, 0, 0);
    }
  }
#pragma unroll
  for (int n = 0; n < 4; ++n)
#pragma unroll
    for (int j = 0; j < 4; ++j)
      P2[(m0 + lg * 4 + j) * ENC + nb + n * 16 + lr] = f2bf(acc[n][j]);
}

// ---------------- single GEMM pass, 128x128 tile, 2-phase double-buffered staging ----------------
// stash raw scores (final permuted layout) + per-(row,depth) exp-sum atomics
template <int BF16S>
__global__ __launch_bounds__(256) void gemm_stash(const unsigned short* __restrict__ P2,
                                                  const unsigned short* __restrict__ E,
                                                  unsigned short* __restrict__ stash,
                                                  float* __restrict__ outp,
                                                  float* __restrict__ S) {
  __shared__ unsigned short SH[2][2][128 * 64];   // [buf][A/B][128 rows x 64 k]
  int tid = threadIdx.x;
  int lane = tid & 63, w = tid >> 6;
  int lr = lane & 15, lg = lane >> 4;
  int wr = w >> 1, wc = w & 1;
  int m0 = blockIdx.x * 128, n0 = blockIdx.y * 128;
  int rr = tid >> 3, c8 = tid & 7;

  f32x4 acc[4][4];
#pragma unroll
  for (int m = 0; m < 4; ++m)
#pragma unroll
    for (int n = 0; n < 4; ++n) acc[m][n] = f32x4{0.f, 0.f, 0.f, 0.f};

#define STAGE(buf, kt)                                                                    \
  _Pragma("unroll") for (int r = 0; r < 4; ++r) {                                         \
    const unsigned short* ga = P2 + (long)(m0 + r * 32 + rr) * ENC + (kt) * 64 + c8 * 8;  \
    __builtin_amdgcn_global_load_lds(                                                     \
        (const __attribute__((address_space(1))) unsigned int*)ga,                        \
        (__attribute__((address_space(3))) unsigned int*)(&SH[buf][0][r * 2048 + w * 512]), \
        16, 0, 0);                                                                        \
    int er = n0 + r * 32 + rr;                                                            \
    if (er > NNODES - 1) er = NNODES - 1;                                                 \
    const unsigned short* gb = E + (long)er * ENC + (kt) * 64 + c8 * 8;                   \
    __builtin_amdgcn_global_load_lds(                                                     \
        (const __attribute__((address_space(1))) unsigned int*)gb,                        \
        (__attribute__((address_space(3))) unsigned int*)(&SH[buf][1][r * 2048 + w * 512]), \
        16, 0, 0);                                                                        \
  }

  STAGE(0, 0)
  __syncthreads();                     // buf0 ready
  for (int kt = 0; kt < 4; ++kt) {
    int cur = kt & 1;
    if (kt < 3) { STAGE(cur ^ 1, kt + 1) }     // prefetch flies under MFMA
    const unsigned short* As = &SH[cur][0][0];
    const unsigned short* Bs = &SH[cur][1][0];
#pragma unroll
    for (int kk = 0; kk < 2; ++kk) {
      bf16x8 a[4], b[4];
#pragma unroll
      for (int m = 0; m < 4; ++m)
        a[m] = *reinterpret_cast<const bf16x8*>(As + (wr * 64 + m * 16 + lr) * 64 + kk * 32 + lg * 8);
#pragma unroll
      for (int n = 0; n < 4; ++n)
        b[n] = *reinterpret_cast<const bf16x8*>(Bs + (wc * 64 + n * 16 + lr) * 64 + kk * 32 + lg * 8);
#pragma unroll
      for (int m = 0; m < 4; ++m)
#pragma unroll
        for (int n = 0; n < 4; ++n)
          acc[m][n] = __builtin_amdgcn_mfma_f32_16x16x32_bf16(a[m], b[n], acc[m][n], 0, 0, 0);
    }
    __syncthreads();                   // drains prefetch vmcnt + ds_reads; buf swap safe
  }
#undef STAGE

  int rbase = m0 + wr * 64 + lg * 4;
  int hstart = n0 + wc * 64;
  // write raw scores to stash (bf16) or out (fp32), final permuted layout
#pragma unroll
  for (int n = 0; n < 4; ++n) {
    int gc = hstart + n * 16 + lr;
    if (gc < NNODES) {
      int d = depth_of(gc);
      long ob = ((long)g_off[d] << 12) + (gc - g_off[d]);
      int sh = 2 * (d + 1);
#pragma unroll
      for (int m = 0; m < 4; ++m)
#pragma unroll
        for (int j = 0; j < 4; ++j) {
          int row = rbase + m * 16 + j;
          long idx = ob + ((long)row << sh);
          if (BF16S) stash[idx] = f2bf(acc[m][n][j]);
          else       outp[idx]  = acc[m][n][j];
        }
    }
  }
  // exp-sum partials (fp32 acc), 16-lane reduce, atomicAdd
  int dlo = depth_of(hstart);
  int hend = hstart + 63; if (hend > NNODES - 1) hend = NNODES - 1;
  int dhi = depth_of(hend);
  int cd[4];
#pragma unroll
  for (int n = 0; n < 4; ++n) {
    int gc = hstart + n * 16 + lr;
    cd[n] = (gc < NNODES) ? depth_of(gc) : 99;
  }
#pragma unroll
  for (int m = 0; m < 4; ++m)
#pragma unroll
    for (int n = 0; n < 4; ++n)
#pragma unroll
      for (int j = 0; j < 4; ++j) acc[m][n][j] = __expf(acc[m][n][j]);
  for (int dt = dlo; dt <= dhi; ++dt) {
#pragma unroll
    for (int m = 0; m < 4; ++m) {
      float s[4] = {0.f, 0.f, 0.f, 0.f};
#pragma unroll
      for (int n = 0; n < 4; ++n) {
        bool use = (cd[n] == dt);
#pragma unroll
        for (int j = 0; j < 4; ++j) s[j] += use ? acc[m][n][j] : 0.f;
      }
#pragma unroll
      for (int j = 0; j < 4; ++j)
#pragma unroll
        for (int o = 1; o < 16; o <<= 1) s[j] += __shfl_xor(s[j], o);
      if (lr == 0) {
#pragma unroll
        for (int j = 0; j < 4; ++j)
          atomicAdd(&S[dt * ROWS + rbase + m * 16 + j], s[j]);
      }
    }
  }
}

// ---------------- pass B: pipelined LDS-staged streaming + fused time head ----------------
// iter = 4096 elems (2 chunks of 2048). Double-buffered 2x8KB LDS: issue next iter's
// global_load_lds BEFORE processing current; one barrier per iter drains it under the
// store burst. blocks [0,256) do the time head first, then join streaming.
__global__ __launch_bounds__(256) void sub_write_lds(const unsigned short* __restrict__ stash,
                                                     const float* __restrict__ S,
                                                     float* __restrict__ out,
                                                     const float* __restrict__ prefix,
                                                     const float* __restrict__ WtT,
                                                     const float* __restrict__ bt) {
  __shared__ unsigned short L[2][4096];   // 16 KB total -> 8 blocks/CU
  int tid = threadIdx.x;
  int lane = tid & 63, w = tid >> 6;

  if (blockIdx.x < 256) {   // ---- time head: 16 rows (4 waves x 4 rows) ----
#pragma unroll
    for (int r4 = 0; r4 < 4; ++r4) {
      int row = (int)blockIdx.x * 16 + w * 4 + r4;
      const float4* pr = reinterpret_cast<const float4*>(prefix + (long)row * HID);
      float acc = -3.4e38f;
      if (lane < NTIMES) {
        float a0 = 0.f, a1 = 0.f, a2 = 0.f, a3 = 0.f;   // 4 indep partials
        for (int q = 0; q < HID / 4; ++q) {
          float4 pv = pr[q];
          const float* wrow = WtT + q * 4 * NTIMES;
          a0 += pv.x * wrow[lane];
          a1 += pv.y * wrow[NTIMES + lane];
          a2 += pv.z * wrow[2 * NTIMES + lane];
          a3 += pv.w * wrow[3 * NTIMES + lane];
        }
        acc = (a0 + a1) + (a2 + a3) + bt[lane];
      }
      float mx = acc;
#pragma unroll
      for (int dd = 32; dd; dd >>= 1) mx = fmaxf(mx, __shfl_xor(mx, dd));
      float e = (lane < NTIMES) ? __expf(acc - mx) : 0.f;
      float sm = e;
#pragma unroll
      for (int dd = 32; dd; dd >>= 1) sm += __shfl_xor(sm, dd);
      if (lane < NTIMES) out[89473024 + row * NTIMES + lane] = acc - mx - __logf(sm);
    }
  }

  // ---- pipelined streaming: 21844 iters x 4096 elems, grid-stride 2304 ----
#define STAGE_SW(buf, it)                                                                 \
  _Pragma("unroll") for (int s = 0; s < 2; ++s) {                                         \
    const unsigned short* src = stash + (long)(it) * 4096 + s * 2048 + tid * 8;           \
    __builtin_amdgcn_global_load_lds(                                                     \
        (const __attribute__((address_space(1))) unsigned int*)src,                       \
        (__attribute__((address_space(3))) unsigned int*)(&L[buf][s * 2048 + (tid >> 6) * 512]), \
        16, 0, 0);                                                                        \
  }

  int it = blockIdx.x;
  if (it >= 21844) return;
  int buf = 0;
  STAGE_SW(0, it)
  __syncthreads();                     // first tile ready
  for (; it < 21844; it += 2304) {
    int nxt = it + 2304;
    if (nxt < 21844) { STAGE_SW(buf ^ 1, nxt) }   // DMA flies under the store burst
    long ibase = (long)it * 4096;
    int itc = it * 2;                  // first 2048-chunk index of this iter
#pragma unroll
    for (int j = 0; j < 4; ++j) {
      int fidx = j * 256 + tid;        // float4 index within iter [0,1024)
      long eidx = ibase + (long)fidx * 4;
      int cc = itc + (j >> 1);         // chunk uniform per j
      int d = (cc >= 8) + (cc >= 40) + (cc >= 168) + (cc >= 680) + (cc >= 2728) + (cc >= 10920);
      long bd = (d == 0) ? 0L : (d == 1) ? 16384L : (d == 2) ? 81920L : (d == 3) ? 344064L
              : (d == 4) ? 1392640L : (d == 5) ? 5586944L : 22364160L;
      int row = (int)((eidx - bd) >> (2 * (d + 1)));   // each float4 = one row (nd >= 4)
      float l = __logf(S[d * ROWS + row]);
      u16x4 u = *reinterpret_cast<const u16x4*>(&L[buf][fidx * 4]);
      float4 o;
      o.x = __uint_as_float((unsigned)(unsigned short)u[0] << 16) - l;
      o.y = __uint_as_float((unsigned)(unsigned short)u[1] << 16) - l;
      o.z = __uint_as_float((unsigned)(unsigned short)u[2] << 16) - l;
      o.w = __uint_as_float((unsigned)(unsigned short)u[3] << 16) - l;
      *reinterpret_cast<float4*>(out + eidx) = o;
    }
    __syncthreads();                   // drains next's DMA (hidden under stores); buf swap safe
    buf ^= 1;
  }
#undef STAGE_SW
}

// ---------------- pass B fallback (fp32 in out): in-place subtract + time head ----------------
__global__ __launch_bounds__(256) void sub_write_inplace(const float* __restrict__ S,
                                                         float* __restrict__ out,
                                                         const float* __restrict__ prefix,
                                                         const float* __restrict__ WtT,
                                                         const float* __restrict__ bt) {
  int tid = threadIdx.x;
  int lane = tid & 63, w = tid >> 6;
  if (blockIdx.x < 256) {   // ---- time head ----
#pragma unroll
    for (int r4 = 0; r4 < 4; ++r4) {
      int row = (int)blockIdx.x * 16 + w * 4 + r4;
      const float4* pr = reinterpret_cast<const float4*>(prefix + (long)row * HID);
      float acc = -3.4e38f;
      if (lane < NTIMES) {
        float a0 = 0.f, a1 = 0.f, a2 = 0.f, a3 = 0.f;
        for (int q = 0; q < HID / 4; ++q) {
          float4 pv = pr[q];
          const float* wrow = WtT + q * 4 * NTIMES;
          a0 += pv.x * wrow[lane];
          a1 += pv.y * wrow[NTIMES + lane];
          a2 += pv.z * wrow[2 * NTIMES + lane];
          a3 += pv.w * wrow[3 * NTIMES + lane];
        }
        acc = (a0 + a1) + (a2 + a3) + bt[lane];
      }
      float mx = acc;
#pragma unroll
      for (int dd = 32; dd; dd >>= 1) mx = fmaxf(mx, __shfl_xor(mx, dd));
      float e = (lane < NTIMES) ? __expf(acc - mx) : 0.f;
      float sm = e;
#pragma unroll
      for (int dd = 32; dd; dd >>= 1) sm += __shfl_xor(sm, dd);
      if (lane < NTIMES) out[89473024 + row * NTIMES + lane] = acc - mx - __logf(sm);
    }
  }
  for (int c = blockIdx.x; c < 43688; c += 2304) {
    long base = (long)c * 2048 + tid * 8;
    int d = (c >= 8) + (c >= 40) + (c >= 168) + (c >= 680) + (c >= 2728) + (c >= 10920);
    long bd = (d == 0) ? 0L : (d == 1) ? 16384L : (d == 2) ? 81920L : (d == 3) ? 344064L
            : (d == 4) ? 1392640L : (d == 5) ? 5586944L : 22364160L;
    long rel = base - bd;
    const float* sp = S + d * ROWS;
    float4 a = reinterpret_cast<const float4*>(out + base)[0];
    float4 b = reinterpret_cast<const float4*>(out + base)[1];
    float4 o0, o1;
    if (d == 0) {
      int r0 = (int)(rel >> 2);
      float l0 = __logf(sp[r0]), l1 = __logf(sp[r0 + 1]);
      o0 = float4{a.x - l0, a.y - l0, a.z - l0, a.w - l0};
      o1 = float4{b.x - l1, b.y - l1, b.z - l1, b.w - l1};
    } else {
      int row = (int)(rel >> (2 * (d + 1)));
      float l = __logf(sp[row]);
      o0 = float4{a.x - l, a.y - l, a.z - l, a.w - l};
      o1 = float4{b.x - l, b.y - l, b.z - l, b.w - l};
    }
    reinterpret_cast<float4*>(out + base)[0] = o0;
    reinterpret_cast<float4*>(out + base)[1] = o1;
  }
}

extern "C" void kernel_launch(void* const* d_in, const int* in_sizes, int n_in,
                              void* d_out, int out_size, void* d_ws, size_t ws_size,
                              hipStream_t stream) {
  const float* prefix = (const float*)d_in[0];  // [128,32,1024]
  const float* emb    = (const float*)d_in[1];  // [21844,256]
  const float* Wk     = (const float*)d_in[2];  // [1024,256]
  const float* Wt     = (const float*)d_in[4];  // [48,1024]
  const float* bt     = (const float*)d_in[5];  // [48]
  float* out = (float*)d_out;
  char* ws = (char*)d_ws;

  // workspace layout (16B aligned)
  unsigned short* P2    = (unsigned short*)(ws + 0);          // 4096*256 bf16
  unsigned short* Eb    = (unsigned short*)(ws + 2097152);    // 21844*256 bf16
  unsigned short* WkT   = (unsigned short*)(ws + 13281280);   // 256*1024 bf16
  unsigned short* Pb16  = (unsigned short*)(ws + 13805568);   // 4096*1024 bf16
  float*          WtT   = (float*)(ws + 22194176);            // 1024*48 f32
  float*          S     = (float*)(ws + 22390784);            // 7*4096 f32
  unsigned short* stash = (unsigned short*)(ws + 22620160);   // 89473024 bf16
  const size_t WS_NEED_STASH = 22620160UL + 178946048UL;      // ~201.6 MB

  bool big = ws_size >= WS_NEED_STASH;

  prep<<<10801, 256, 0, stream>>>(prefix, emb, Wk, Wt, Pb16, Eb, WkT, WtT, S);

  p2_mfma<<<dim3(4, 64), 256, 0, stream>>>(Pb16, WkT, P2);

  if (big) {
    gemm_stash<1><<<dim3(32, 171), 256, 0, stream>>>(P2, Eb, stash, out, S);
    sub_write_lds<<<2304, 256, 0, stream>>>(stash, S, out, prefix, WtT, bt);
  } else {
    gemm_stash<0><<<dim3(32, 171), 256, 0, stream>>>(P2, Eb, stash, out, S);
    sub_write_inplace<<<2304, 256, 0, stream>>>(S, out, prefix, WtT, bt);
  }
}

// Round 19
// 336.248 us; speedup vs baseline: 1.0109x; 1.0109x over previous
//
#include <hip/hip_runtime.h>

#define NNODES 21844
#define ENC 256
#define HID 1024
#define ROWS 4096   // B*S = 128*32
#define NTIMES 48

typedef __attribute__((ext_vector_type(8))) short bf16x8;
typedef __attribute__((ext_vector_type(8))) unsigned short u16x8;
typedef __attribute__((ext_vector_type(4))) unsigned short u16x4;
typedef __attribute__((ext_vector_type(4))) float f32x4;

__device__ const int g_off[8] = {0, 4, 20, 84, 340, 1364, 5460, 21844};

__device__ inline unsigned short f2bf(float f) {
  unsigned int u = __float_as_uint(f);
  u += 0x7FFF + ((u >> 16) & 1);   // round-to-nearest-even
  return (unsigned short)(u >> 16);
}

__device__ inline int depth_of(int c) {
  return (c >= 4) + (c >= 20) + (c >= 84) + (c >= 340) + (c >= 1364) + (c >= 5460);
}

// ---------------- fused preprocessing: conversions + transposes + S zeroing ----------------
__global__ __launch_bounds__(256) void prep(const float* __restrict__ prefix,
                                            const float* __restrict__ emb,
                                            const float* __restrict__ Wk,
                                            const float* __restrict__ Wt,
                                            unsigned short* __restrict__ Pb16,
                                            unsigned short* __restrict__ Eb,
                                            unsigned short* __restrict__ WkT,
                                            float* __restrict__ WtT,
                                            float* __restrict__ S) {
  int bid = blockIdx.x, tid = threadIdx.x;
  if (bid < 4096) {                          // prefix fp32 -> bf16
    int i = bid * 256 + tid;
    float4 v = reinterpret_cast<const float4*>(prefix)[i];
    ushort4 o; o.x = f2bf(v.x); o.y = f2bf(v.y); o.z = f2bf(v.z); o.w = f2bf(v.w);
    reinterpret_cast<ushort4*>(Pb16)[i] = o;
  } else if (bid < 9557) {                   // emb fp32 -> bf16
    int i = (bid - 4096) * 256 + tid;
    float4 v = reinterpret_cast<const float4*>(emb)[i];
    ushort4 o; o.x = f2bf(v.x); o.y = f2bf(v.y); o.z = f2bf(v.z); o.w = f2bf(v.w);
    reinterpret_cast<ushort4*>(Eb)[i] = o;
  } else if (bid < 10581) {                  // W_key [1024,256] -> bf16 T [256,1024]
    int i = (bid - 9557) * 256 + tid;
    int e = i >> 10, h = i & 1023;
    WkT[i] = f2bf(Wk[h * ENC + e]);
  } else if (bid < 10773) {                  // W_time [48,1024] -> f32 T [1024,48]
    int i = (bid - 10581) * 256 + tid;
    int k = i / NTIMES, c = i % NTIMES;
    WtT[i] = Wt[c * HID + k];
  } else {                                   // zero S (7*4096 floats = 7168 float4)
    int i = (bid - 10773) * 256 + tid;
    reinterpret_cast<float4*>(S)[i] = float4{0.f, 0.f, 0.f, 0.f};
  }
}

// ---------------- P2 = prefix @ W_key  (bf16 MFMA, K=1024) -> bf16 [4096,256] ----------------
__global__ __launch_bounds__(256) void p2_mfma(const unsigned short* __restrict__ Ab,
                                               const unsigned short* __restrict__ Bb,
                                               unsigned short* __restrict__ P2) {
  int lane = threadIdx.x & 63, w = threadIdx.x >> 6;
  int lr = lane & 15, lg = lane >> 4;
  int m0 = blockIdx.y * 64 + w * 16;
  int nb = blockIdx.x * 64;
  f32x4 acc[4];
#pragma unroll
  for (int n = 0; n < 4; ++n) acc[n] = f32x4{0.f, 0.f, 0.f, 0.f};
  const unsigned short* Ap = Ab + (long)(m0 + lr) * HID + lg * 8;
  for (int kk = 0; kk < 32; ++kk) {
    bf16x8 a = *reinterpret_cast<const bf16x8*>(Ap + kk * 32);
#pragma unroll
    for (int n = 0; n < 4; ++n) {
      bf16x8 b = *reinterpret_cast<const bf16x8*>(Bb + (long)(nb + n * 16 + lr) * HID + kk * 32 + lg * 8);
      acc[n] = __builtin_amdgcn_mfma_f32_16x16x32_bf16(a, b, acc[n], 0, 0, 0);
    }
  }
#pragma unroll
  for (int n = 0; n < 4; ++n)
#pragma unroll
    for (int j = 0; j < 4; ++j)
      P2[(m0 + lg * 4 + j) * ENC + nb + n * 16 + lr] = f2bf(acc[n][j]);
}

// ---------------- single GEMM pass, 128x128 tile, 2-phase double-buffered staging ----------------
// stash raw scores (final permuted layout) + per-(row,depth) exp-sum atomics
template <int BF16S>
__global__ __launch_bounds__(256) void gemm_stash(const unsigned short* __restrict__ P2,
                                                  const unsigned short* __restrict__ E,
                                                  unsigned short* __restrict__ stash,
                                                  float* __restrict__ outp,
                                                  float* __restrict__ S) {
  __shared__ unsigned short SH[2][2][128 * 64];   // [buf][A/B][128 rows x 64 k]
  int tid = threadIdx.x;
  int lane = tid & 63, w = tid >> 6;
  int lr = lane & 15, lg = lane >> 4;
  int wr = w >> 1, wc = w & 1;
  int m0 = blockIdx.x * 128, n0 = blockIdx.y * 128;
  int rr = tid >> 3, c8 = tid & 7;

  f32x4 acc[4][4];
#pragma unroll
  for (int m = 0; m < 4; ++m)
#pragma unroll
    for (int n = 0; n < 4; ++n) acc[m][n] = f32x4{0.f, 0.f, 0.f, 0.f};

#define STAGE(buf, kt)                                                                    \
  _Pragma("unroll") for (int r = 0; r < 4; ++r) {                                         \
    const unsigned short* ga = P2 + (long)(m0 + r * 32 + rr) * ENC + (kt) * 64 + c8 * 8;  \
    __builtin_amdgcn_global_load_lds(                                                     \
        (const __attribute__((address_space(1))) unsigned int*)ga,                        \
        (__attribute__((address_space(3))) unsigned int*)(&SH[buf][0][r * 2048 + w * 512]), \
        16, 0, 0);                                                                        \
    int er = n0 + r * 32 + rr;                                                            \
    if (er > NNODES - 1) er = NNODES - 1;                                                 \
    const unsigned short* gb = E + (long)er * ENC + (kt) * 64 + c8 * 8;                   \
    __builtin_amdgcn_global_load_lds(                                                     \
        (const __attribute__((address_space(1))) unsigned int*)gb,                        \
        (__attribute__((address_space(3))) unsigned int*)(&SH[buf][1][r * 2048 + w * 512]), \
        16, 0, 0);                                                                        \
  }

  STAGE(0, 0)
  __syncthreads();                     // buf0 ready
  for (int kt = 0; kt < 4; ++kt) {
    int cur = kt & 1;
    if (kt < 3) { STAGE(cur ^ 1, kt + 1) }     // prefetch flies under MFMA
    const unsigned short* As = &SH[cur][0][0];
    const unsigned short* Bs = &SH[cur][1][0];
#pragma unroll
    for (int kk = 0; kk < 2; ++kk) {
      bf16x8 a[4], b[4];
#pragma unroll
      for (int m = 0; m < 4; ++m)
        a[m] = *reinterpret_cast<const bf16x8*>(As + (wr * 64 + m * 16 + lr) * 64 + kk * 32 + lg * 8);
#pragma unroll
      for (int n = 0; n < 4; ++n)
        b[n] = *reinterpret_cast<const bf16x8*>(Bs + (wc * 64 + n * 16 + lr) * 64 + kk * 32 + lg * 8);
#pragma unroll
      for (int m = 0; m < 4; ++m)
#pragma unroll
        for (int n = 0; n < 4; ++n)
          acc[m][n] = __builtin_amdgcn_mfma_f32_16x16x32_bf16(a[m], b[n], acc[m][n], 0, 0, 0);
    }
    __syncthreads();                   // drains prefetch vmcnt + ds_reads; buf swap safe
  }
#undef STAGE

  int rbase = m0 + wr * 64 + lg * 4;
  int hstart = n0 + wc * 64;
  // write raw scores to stash (bf16) or out (fp32), final permuted layout
#pragma unroll
  for (int n = 0; n < 4; ++n) {
    int gc = hstart + n * 16 + lr;
    if (gc < NNODES) {
      int d = depth_of(gc);
      long ob = ((long)g_off[d] << 12) + (gc - g_off[d]);
      int sh = 2 * (d + 1);
#pragma unroll
      for (int m = 0; m < 4; ++m)
#pragma unroll
        for (int j = 0; j < 4; ++j) {
          int row = rbase + m * 16 + j;
          long idx = ob + ((long)row << sh);
          if (BF16S) stash[idx] = f2bf(acc[m][n][j]);
          else       outp[idx]  = acc[m][n][j];
        }
    }
  }
  // exp-sum partials (fp32 acc), 16-lane reduce, atomicAdd
  int dlo = depth_of(hstart);
  int hend = hstart + 63; if (hend > NNODES - 1) hend = NNODES - 1;
  int dhi = depth_of(hend);
  int cd[4];
#pragma unroll
  for (int n = 0; n < 4; ++n) {
    int gc = hstart + n * 16 + lr;
    cd[n] = (gc < NNODES) ? depth_of(gc) : 99;
  }
#pragma unroll
  for (int m = 0; m < 4; ++m)
#pragma unroll
    for (int n = 0; n < 4; ++n)
#pragma unroll
      for (int j = 0; j < 4; ++j) acc[m][n][j] = __expf(acc[m][n][j]);
  for (int dt = dlo; dt <= dhi; ++dt) {
#pragma unroll
    for (int m = 0; m < 4; ++m) {
      float s[4] = {0.f, 0.f, 0.f, 0.f};
#pragma unroll
      for (int n = 0; n < 4; ++n) {
        bool use = (cd[n] == dt);
#pragma unroll
        for (int j = 0; j < 4; ++j) s[j] += use ? acc[m][n][j] : 0.f;
      }
#pragma unroll
      for (int j = 0; j < 4; ++j)
#pragma unroll
        for (int o = 1; o < 16; o <<= 1) s[j] += __shfl_xor(s[j], o);
      if (lr == 0) {
#pragma unroll
        for (int j = 0; j < 4; ++j)
          atomicAdd(&S[dt * ROWS + rbase + m * 16 + j], s[j]);
      }
    }
  }
}

// ---------------- pass B: persistent LDS-staged bulk streaming + fused time head ----------------
// blocks [0,256): time head (16 rows each) first, then join streaming.
// streaming: grid-stride over 10922 iters of 8192 elems (stage 16KB -> LDS, store 32KB fp32).
__global__ __launch_bounds__(256) void sub_write_lds(const unsigned short* __restrict__ stash,
                                                     const float* __restrict__ S,
                                                     float* __restrict__ out,
                                                     const float* __restrict__ prefix,
                                                     const float* __restrict__ WtT,
                                                     const float* __restrict__ bt) {
  __shared__ unsigned short L[8192];   // 16 KB -> 8 blocks/CU
  int tid = threadIdx.x;
  int lane = tid & 63, w = tid >> 6;

  if (blockIdx.x < 256) {   // ---- time head: 16 rows (4 waves x 4 rows) ----
#pragma unroll
    for (int r4 = 0; r4 < 4; ++r4) {
      int row = (int)blockIdx.x * 16 + w * 4 + r4;
      const float4* pr = reinterpret_cast<const float4*>(prefix + (long)row * HID);
      float acc = -3.4e38f;
      if (lane < NTIMES) {
        float a0 = 0.f, a1 = 0.f, a2 = 0.f, a3 = 0.f;   // 4 indep partials
        for (int q = 0; q < HID / 4; ++q) {
          float4 pv = pr[q];
          const float* wrow = WtT + q * 4 * NTIMES;
          a0 += pv.x * wrow[lane];
          a1 += pv.y * wrow[NTIMES + lane];
          a2 += pv.z * wrow[2 * NTIMES + lane];
          a3 += pv.w * wrow[3 * NTIMES + lane];
        }
        acc = (a0 + a1) + (a2 + a3) + bt[lane];
      }
      float mx = acc;
#pragma unroll
      for (int dd = 32; dd; dd >>= 1) mx = fmaxf(mx, __shfl_xor(mx, dd));
      float e = (lane < NTIMES) ? __expf(acc - mx) : 0.f;
      float sm = e;
#pragma unroll
      for (int dd = 32; dd; dd >>= 1) sm += __shfl_xor(sm, dd);
      if (lane < NTIMES) out[89473024 + row * NTIMES + lane] = acc - mx - __logf(sm);
    }
  }

  // ---- streaming ----
  for (int it = blockIdx.x; it < 10922; it += 2304) {
    long ibase = (long)it * 8192;
    int itc = it * 4;                  // first 2048-elem chunk index of this iter
#pragma unroll
    for (int s = 0; s < 4; ++s) {
      const unsigned short* src = stash + ibase + s * 2048 + tid * 8;
      __builtin_amdgcn_global_load_lds(
          (const __attribute__((address_space(1))) unsigned int*)src,
          (__attribute__((address_space(3))) unsigned int*)(&L[s * 2048 + (tid >> 6) * 512]),
          16, 0, 0);
    }
    __syncthreads();                   // drains vmcnt; LDS ready
#pragma unroll
    for (int j = 0; j < 8; ++j) {
      int fidx = j * 256 + tid;        // float4 index within iter [0,2048)
      long eidx = ibase + (long)fidx * 4;
      int cc = itc + (j >> 1);         // chunk uniform per j
      int d = (cc >= 8) + (cc >= 40) + (cc >= 168) + (cc >= 680) + (cc >= 2728) + (cc >= 10920);
      long bd = (d == 0) ? 0L : (d == 1) ? 16384L : (d == 2) ? 81920L : (d == 3) ? 344064L
              : (d == 4) ? 1392640L : (d == 5) ? 5586944L : 22364160L;
      int row = (int)((eidx - bd) >> (2 * (d + 1)));
      float l = __logf(S[d * ROWS + row]);
      u16x4 u = *reinterpret_cast<const u16x4*>(&L[fidx * 4]);
      float4 o;
      o.x = __uint_as_float((unsigned)(unsigned short)u[0] << 16) - l;
      o.y = __uint_as_float((unsigned)(unsigned short)u[1] << 16) - l;
      o.z = __uint_as_float((unsigned)(unsigned short)u[2] << 16) - l;
      o.w = __uint_as_float((unsigned)(unsigned short)u[3] << 16) - l;
      *reinterpret_cast<float4*>(out + eidx) = o;
    }
    __syncthreads();                   // L reuse safe next iter
  }
}

// ---------------- pass B fallback (fp32 in out): in-place subtract + time head ----------------
__global__ __launch_bounds__(256) void sub_write_inplace(const float* __restrict__ S,
                                                         float* __restrict__ out,
                                                         const float* __restrict__ prefix,
                                                         const float* __restrict__ WtT,
                                                         const float* __restrict__ bt) {
  int tid = threadIdx.x;
  int lane = tid & 63, w = tid >> 6;
  if (blockIdx.x < 256) {   // ---- time head ----
#pragma unroll
    for (int r4 = 0; r4 < 4; ++r4) {
      int row = (int)blockIdx.x * 16 + w * 4 + r4;
      const float4* pr = reinterpret_cast<const float4*>(prefix + (long)row * HID);
      float acc = -3.4e38f;
      if (lane < NTIMES) {
        float a0 = 0.f, a1 = 0.f, a2 = 0.f, a3 = 0.f;
        for (int q = 0; q < HID / 4; ++q) {
          float4 pv = pr[q];
          const float* wrow = WtT + q * 4 * NTIMES;
          a0 += pv.x * wrow[lane];
          a1 += pv.y * wrow[NTIMES + lane];
          a2 += pv.z * wrow[2 * NTIMES + lane];
          a3 += pv.w * wrow[3 * NTIMES + lane];
        }
        acc = (a0 + a1) + (a2 + a3) + bt[lane];
      }
      float mx = acc;
#pragma unroll
      for (int dd = 32; dd; dd >>= 1) mx = fmaxf(mx, __shfl_xor(mx, dd));
      float e = (lane < NTIMES) ? __expf(acc - mx) : 0.f;
      float sm = e;
#pragma unroll
      for (int dd = 32; dd; dd >>= 1) sm += __shfl_xor(sm, dd);
      if (lane < NTIMES) out[89473024 + row * NTIMES + lane] = acc - mx - __logf(sm);
    }
  }
  for (int c = blockIdx.x; c < 43688; c += 2304) {
    long base = (long)c * 2048 + tid * 8;
    int d = (c >= 8) + (c >= 40) + (c >= 168) + (c >= 680) + (c >= 2728) + (c >= 10920);
    long bd = (d == 0) ? 0L : (d == 1) ? 16384L : (d == 2) ? 81920L : (d == 3) ? 344064L
            : (d == 4) ? 1392640L : (d == 5) ? 5586944L : 22364160L;
    long rel = base - bd;
    const float* sp = S + d * ROWS;
    float4 a = reinterpret_cast<const float4*>(out + base)[0];
    float4 b = reinterpret_cast<const float4*>(out + base)[1];
    float4 o0, o1;
    if (d == 0) {
      int r0 = (int)(rel >> 2);
      float l0 = __logf(sp[r0]), l1 = __logf(sp[r0 + 1]);
      o0 = float4{a.x - l0, a.y - l0, a.z - l0, a.w - l0};
      o1 = float4{b.x - l1, b.y - l1, b.z - l1, b.w - l1};
    } else {
      int row = (int)(rel >> (2 * (d + 1)));
      float l = __logf(sp[row]);
      o0 = float4{a.x - l, a.y - l, a.z - l, a.w - l};
      o1 = float4{b.x - l, b.y - l, b.z - l, b.w - l};
    }
    reinterpret_cast<float4*>(out + base)[0] = o0;
    reinterpret_cast<float4*>(out + base)[1] = o1;
  }
}

extern "C" void kernel_launch(void* const* d_in, const int* in_sizes, int n_in,
                              void* d_out, int out_size, void* d_ws, size_t ws_size,
                              hipStream_t stream) {
  const float* prefix = (const float*)d_in[0];  // [128,32,1024]
  const float* emb    = (const float*)d_in[1];  // [21844,256]
  const float* Wk     = (const float*)d_in[2];  // [1024,256]
  const float* Wt     = (const float*)d_in[4];  // [48,1024]
  const float* bt     = (const float*)d_in[5];  // [48]
  float* out = (float*)d_out;
  char* ws = (char*)d_ws;

  // workspace layout (16B aligned)
  unsigned short* P2    = (unsigned short*)(ws + 0);          // 4096*256 bf16
  unsigned short* Eb    = (unsigned short*)(ws + 2097152);    // 21844*256 bf16
  unsigned short* WkT   = (unsigned short*)(ws + 13281280);   // 256*1024 bf16
  unsigned short* Pb16  = (unsigned short*)(ws + 13805568);   // 4096*1024 bf16
  float*          WtT   = (float*)(ws + 22194176);            // 1024*48 f32
  float*          S     = (float*)(ws + 22390784);            // 7*4096 f32
  unsigned short* stash = (unsigned short*)(ws + 22620160);   // 89473024 bf16
  const size_t WS_NEED_STASH = 22620160UL + 178946048UL;      // ~201.6 MB

  bool big = ws_size >= WS_NEED_STASH;

  prep<<<10801, 256, 0, stream>>>(prefix, emb, Wk, Wt, Pb16, Eb, WkT, WtT, S);

  p2_mfma<<<dim3(4, 64), 256, 0, stream>>>(Pb16, WkT, P2);

  if (big) {
    gemm_stash<1><<<dim3(32, 171), 256, 0, stream>>>(P2, Eb, stash, out, S);
    sub_write_lds<<<2304, 256, 0, stream>>>(stash, S, out, prefix, WtT, bt);
  } else {
    gemm_stash<0><<<dim3(32, 171), 256, 0, stream>>>(P2, Eb, stash, out, S);
    sub_write_inplace<<<2304, 256, 0, stream>>>(S, out, prefix, WtT, bt);
  }
}